// Round 4
// baseline (201.193 us; speedup 1.0000x reference)
//
#include <hip/hip_runtime.h>
#include <math.h>

// Problem constants
#define B_N   4
#define CIN   21
#define HIDC  48
#define H0    81
#define NP    6561      // 81*81
#define HH    324
#define NPH   104976    // 324*324

__device__ __forceinline__ float tanh_fast(float x) {
    float e = __expf(2.f * x);
    return 1.f - 2.f / (e + 1.f);
}

// ---------------------------------------------------------------------------
// K1 v6 (unchanged): conv1 both heads (21 -> 96 = 48 o + 48 g), relu.
// ---------------------------------------------------------------------------
__global__ __launch_bounds__(256) void k1_conv1(
    const float* __restrict__ x,
    const float* __restrict__ w1o, const float* __restrict__ b1o,
    const float* __restrict__ w1g, const float* __restrict__ b1g,
    float* __restrict__ hid_o, float* __restrict__ hid_g)
{
    __shared__ __align__(16) float wt[189 * 12];  // [ict*12 + oc]
    __shared__ float bs[12];
    const int tid = threadIdx.x;
    const int grp = blockIdx.y;          // 0..7 ; 0..3 -> head_o, 4..7 -> head_g
    const int b   = blockIdx.z;
    const bool head_o = (grp < 4);
    const int ocb = (grp & 3) * 12;      // oc base within the head
    const float* wsrc = head_o ? w1o : w1g;
    for (int i = tid; i < 189 * 12; i += 256) {
        const int ict = i / 12, oc = i - ict * 12;
        wt[i] = wsrc[(ocb + oc) * 189 + ict];
    }
    if (tid < 12) bs[tid] = (head_o ? b1o : b1g)[ocb + tid];
    __syncthreads();

    const int px = blockIdx.x * 256 + tid;
    const bool valid = (px < NP);
    const int oy = px / H0, ox = px - oy * H0;
    const float* xb = x + (size_t)b * CIN * NP;

    float acc[12];
    #pragma unroll
    for (int j = 0; j < 12; j++) acc[j] = bs[j];

    for (int ic = 0; ic < CIN; ic++) {
        const float* xc = xb + ic * NP;
        float xv[9];
        #pragma unroll
        for (int ky = 0; ky < 3; ky++) {
            const int iy = oy + ky - 1;
            const bool rok = valid && ((unsigned)iy < (unsigned)H0);
            #pragma unroll
            for (int kx = 0; kx < 3; kx++) {
                const int ix = ox + kx - 1;
                const bool ok = rok && ((unsigned)ix < (unsigned)H0);
                xv[ky * 3 + kx] = ok ? xc[iy * H0 + ix] : 0.f;
            }
        }
        #pragma unroll
        for (int tap = 0; tap < 9; tap++) {
            const float4 w0 = *(const float4*)&wt[(ic * 9 + tap) * 12];
            const float4 w1 = *(const float4*)&wt[(ic * 9 + tap) * 12 + 4];
            const float4 w2 = *(const float4*)&wt[(ic * 9 + tap) * 12 + 8];
            const float wj[12] = {w0.x, w0.y, w0.z, w0.w, w1.x, w1.y, w1.z, w1.w,
                                  w2.x, w2.y, w2.z, w2.w};
            const float xvt = xv[tap];
            #pragma unroll
            for (int j = 0; j < 12; j++) acc[j] = fmaf(xvt, wj[j], acc[j]);
        }
    }

    if (valid) {
        float* outp = (head_o ? hid_o : hid_g) + ((size_t)b * HIDC + ocb) * NP + px;
        #pragma unroll
        for (int j = 0; j < 12; j++) outp[j * NP] = fmaxf(acc[j], 0.f);
    }
}

// ---------------------------------------------------------------------------
// K2UP v2: conv2+masks+upsample, with x 3x3 windows PREFETCHED into registers
// at kernel start (latency hidden under the conv phase). Each thread owns
// fixed (c, pl) items: pl = tid&31, c in {s, s+8, s+16} (s = tid>>5; the
// s==5 third item is the g_up plane). After the mask barrier the emit phase
// is pure register/LDS math + coalesced float4 stores: no global loads, no
// alp2/ahp2 round-trip, one fewer barrier than v1.
// All xw indexing is compile-time (no scratch); runtime sy/sx -> cndmask.
// ---------------------------------------------------------------------------
__global__ __launch_bounds__(256, 3) void k2up(
    const float* __restrict__ x,
    const float* __restrict__ hid_o, const float* __restrict__ hid_g,
    const float* __restrict__ w2o, const float* __restrict__ b2o,
    const float* __restrict__ w2g, const float* __restrict__ b2g,
    const float* __restrict__ beta,
    float* __restrict__ v_out, float* __restrict__ y_out,
    float* __restrict__ gup_out)
{
    __shared__ __align__(16) float wo_s[HIDC * 9 * 8];  // [(ic*9+tap)*8 + d]
    __shared__ float wg_s[HIDC * 9];
    __shared__ float red[4][32][12];
    __shared__ float res_s[32][29];     // stride 29 coprime w/ 32 banks
    const int tid = threadIdx.x;
    const int b = blockIdx.y;

    const int pl  = tid & 31;
    const int s   = tid >> 5;                // 0..7
    const int w   = tid >> 6;                // wave
    const int px0 = blockIdx.x * 32;
    const int px  = px0 + pl;
    const bool valid = (px < NP);
    const int py  = px / H0, pxc = px - py * H0;

    // ---- prefetch x 3x3 reflect-windows for my (c, pl) items ------------
    // issued FIRST: these vmem loads retire during the conv phase.
    float xw0[9], xw1[9], xw2[9];
    {
        const int ym = (py == 0) ? 1 : py - 1;
        const int yp = (py == H0 - 1) ? H0 - 2 : py + 1;
        const int xm = (pxc == 0) ? 1 : pxc - 1;
        const int xp = (pxc == H0 - 1) ? H0 - 2 : pxc + 1;
        const int ro[3] = {ym * H0, py * H0, yp * H0};
        const int co[3] = {xm, pxc, xp};
        if (valid) {
            const float* xb0 = x + ((size_t)b * CIN + s) * NP;        // c = s (0..7)
            const float* xb1 = xb0 + 8 * NP;                          // c = s+8 (8..15)
            #pragma unroll
            for (int t = 0; t < 3; t++)
                #pragma unroll
                for (int u = 0; u < 3; u++) {
                    xw0[t * 3 + u] = xb0[ro[t] + co[u]];
                    xw1[t * 3 + u] = xb1[ro[t] + co[u]];
                }
            if (s < 5) {
                const float* xb2 = xb0 + 16 * NP;                     // c = s+16 (16..20)
                #pragma unroll
                for (int t = 0; t < 3; t++)
                    #pragma unroll
                    for (int u = 0; u < 3; u++)
                        xw2[t * 3 + u] = xb2[ro[t] + co[u]];
            }
        }
    }

    // ---- stage conv2 weights --------------------------------------------
    for (int i = tid; i < HIDC * 9 * 8; i += 256) {
        const int d = i / (HIDC * 9), r = i - d * (HIDC * 9);
        wo_s[r * 8 + d] = w2o[i];
    }
    for (int i = tid; i < HIDC * 9; i += 256) wg_s[i] = w2g[i];
    __syncthreads();

    // ---- conv2 partials (unchanged structure) ---------------------------
    const int ic0 = s * 6;
    const float* po = hid_o + ((size_t)b * HIDC + ic0) * NP;
    const float* pg = hid_g + ((size_t)b * HIDC + ic0) * NP;

    float a[8] = {0.f, 0.f, 0.f, 0.f, 0.f, 0.f, 0.f, 0.f};
    float ag = 0.f;

    #pragma unroll 1
    for (int ky = 0; ky < 3; ky++) {
        const int iy = py + ky - 1;
        const bool rok = valid && ((unsigned)iy < (unsigned)H0);
        #pragma unroll
        for (int kx = 0; kx < 3; kx++) {
            const int ix = pxc + kx - 1;
            const bool ok = rok && ((unsigned)ix < (unsigned)H0);
            const int off = iy * H0 + ix;
            const int tap = ky * 3 + kx;
            #pragma unroll
            for (int j = 0; j < 6; j++) {
                const float vo = ok ? po[j * NP + off] : 0.f;
                const float vg = ok ? pg[j * NP + off] : 0.f;
                const int wb = ((ic0 + j) * 9 + tap) * 8;
                const float4 wA = *(const float4*)&wo_s[wb];
                const float4 wB = *(const float4*)&wo_s[wb + 4];
                a[0] = fmaf(vo, wA.x, a[0]); a[1] = fmaf(vo, wA.y, a[1]);
                a[2] = fmaf(vo, wA.z, a[2]); a[3] = fmaf(vo, wA.w, a[3]);
                a[4] = fmaf(vo, wB.x, a[4]); a[5] = fmaf(vo, wB.y, a[5]);
                a[6] = fmaf(vo, wB.z, a[6]); a[7] = fmaf(vo, wB.w, a[7]);
                ag = fmaf(vg, wg_s[(ic0 + j) * 9 + tap], ag);
            }
        }
    }

    #pragma unroll
    for (int n = 0; n < 8; n++) a[n] += __shfl_xor(a[n], 32);
    ag += __shfl_xor(ag, 32);
    if ((tid & 32) == 0) {
        #pragma unroll
        for (int n = 0; n < 8; n++) red[w][pl][n] = a[n];
        red[w][pl][8] = ag;
    }
    __syncthreads();

    // ---- mask epilogue (32 threads) -------------------------------------
    if (tid < 32 && valid) {
        float v[8];
        #pragma unroll
        for (int n = 0; n < 8; n++)
            v[n] = tanh_fast(red[0][tid][n] + red[1][tid][n] + red[2][tid][n]
                             + red[3][tid][n] + b2o[n]);
        const float agf = red[0][tid][8] + red[1][tid][8] + red[2][tid][8]
                        + red[3][tid][8] + b2g[0];
        const float g = 1.f / (1.f + __expf(-agf));

        constexpr float DT[8][9] = {
            {-1, 0, 1, -1, 0, 1, -1, 0, 1},
            {-1,-1, 0, -1, 0, 1,  0, 1, 1},
            {-1,-1,-1,  0, 0, 0,  1, 1, 1},
            { 0,-1,-1,  1, 0,-1,  1, 1, 0},
            { 1, 0,-1,  1, 0,-1,  1, 0,-1},
            { 1, 1, 0,  1, 0,-1,  0,-1,-1},
            { 1, 1, 1,  0, 0, 0, -1,-1,-1},
            { 0, 1, 1, -1, 0, 1, -1,-1, 0}};
        float ker[9];
        #pragma unroll
        for (int n = 0; n < 9; n++) {
            float t = 0.f;
            #pragma unroll
            for (int d = 0; d < 8; d++) t += v[d] * DT[d][n];
            ker[n] = -0.125f * t;
        }
        ker[4] += 2.5f;
        float mx = ker[0];
        #pragma unroll
        for (int n = 1; n < 9; n++) mx = fmaxf(mx, ker[n]);
        float exn[9], sum = 0.f;
        #pragma unroll
        for (int n = 0; n < 9; n++) { exn[n] = __expf((ker[n] - mx) * 2.0f); sum += exn[n]; }
        const float rs = 1.f / sum;
        float mean = 0.f;
        #pragma unroll
        for (int n = 0; n < 9; n++) mean += ker[n];
        mean *= (1.f / 9.f);
        float den = 1e-8f;
        #pragma unroll
        for (int n = 0; n < 9; n++) den += fabsf(ker[n] - mean);
        const float rd = 1.f / den;

        #pragma unroll
        for (int n = 0; n < 8; n++) res_s[tid][n] = v[n];
        res_s[tid][8] = g;
        #pragma unroll
        for (int n = 0; n < 9; n++) {
            res_s[tid][9 + n]  = exn[n] * rs;
            res_s[tid][18 + n] = (ker[n] - mean) * rd;
        }
    }
    __syncthreads();

    // ---- v scatter (one iteration: 8 planes x 32 px) --------------------
    if (px0 + pl < NP) v_out[((size_t)b * 8 + s) * NP + px0 + pl] = res_s[pl][s];

    // ---- emit: alp/ahp + 4 hi-res rows per owned item, all from regs ----
    if (valid) {
        const float tb  = tanh_fast(beta[0]);
        const float gv  = res_s[pl][8];
        const float lam = 0.15f * (1.f - gv);
        const float gh  = tb * gv;

        // per-pixel bilinear coefficients (shared across items)
        int syv[4]; float wyv[4];
        #pragma unroll
        for (int dh = 0; dh < 4; dh++) {
            const int H = py * 4 + dh;
            const float ysf = (float)H * (80.f / 323.f);
            int y0 = (int)ysf;
            if (y0 > H0 - 2) y0 = H0 - 2;
            wyv[dh] = ysf - (float)y0;
            syv[dh] = y0 - py + 1;       // 0 or 1 (proved at all edges)
        }
        int sxv[4]; float wxv[4];
        #pragma unroll
        for (int k = 0; k < 4; k++) {
            const int W = pxc * 4 + k;
            const float xsf = (float)W * (80.f / 323.f);
            int x0 = (int)xsf;
            if (x0 > H0 - 2) x0 = H0 - 2;
            wxv[k] = xsf - (float)x0;
            sxv[k] = x0 - pxc + 1;       // 0 or 1
        }

#define EMIT_PLANE(CC, XW) do {                                              \
        float alp = 0.f, ahp = 0.f;                                          \
        _Pragma("unroll")                                                    \
        for (int t = 0; t < 9; t++) {                                        \
            alp = fmaf(XW[t], res_s[pl][9 + t],  alp);                       \
            ahp = fmaf(XW[t], res_s[pl][18 + t], ahp);                       \
        }                                                                    \
        float* ydst = y_out + ((size_t)b * CIN + (CC)) * NPH;                \
        _Pragma("unroll")                                                    \
        for (int dh = 0; dh < 4; dh++) {                                     \
            const int sy = syv[dh];                                          \
            const float wy = wyv[dh];                                        \
            const float A0 = sy ? XW[3] : XW[0];                             \
            const float A1 = sy ? XW[4] : XW[1];                             \
            const float A2 = sy ? XW[5] : XW[2];                             \
            const float B0 = sy ? XW[6] : XW[3];                             \
            const float B1 = sy ? XW[7] : XW[4];                             \
            const float B2 = sy ? XW[8] : XW[5];                             \
            float rr[4];                                                     \
            _Pragma("unroll")                                                \
            for (int k = 0; k < 4; k++) {                                    \
                const float wx = wxv[k];                                     \
                const float top = sxv[k] ? fmaf(A2 - A1, wx, A1)             \
                                         : fmaf(A1 - A0, wx, A0);            \
                const float bot = sxv[k] ? fmaf(B2 - B1, wx, B1)             \
                                         : fmaf(B1 - B0, wx, B0);            \
                const float xup = fmaf(bot - top, wy, top);                  \
                rr[k] = fmaf(lam, alp - xup, xup) + gh * ahp;                \
            }                                                                \
            *reinterpret_cast<float4*>(ydst + (size_t)(py * 4 + dh) * HH     \
                                       + pxc * 4) =                          \
                make_float4(rr[0], rr[1], rr[2], rr[3]);                     \
        }                                                                    \
    } while (0)

        EMIT_PLANE(s,     xw0);
        EMIT_PLANE(s + 8, xw1);
        if (s < 5) {
            EMIT_PLANE(s + 16, xw2);
        } else if (s == 5) {
            // g_up plane: 4 hi-res rows of replicated gate
            float* gdst = gup_out + (size_t)b * NPH;
            #pragma unroll
            for (int dh = 0; dh < 4; dh++)
                *reinterpret_cast<float4*>(gdst + (size_t)(py * 4 + dh) * HH + pxc * 4) =
                    make_float4(gv, gv, gv, gv);
        }
#undef EMIT_PLANE
    }
}

// ---------------------------------------------------------------------------
extern "C" void kernel_launch(void* const* d_in, const int* in_sizes, int n_in,
                              void* d_out, int out_size, void* d_ws, size_t ws_size,
                              hipStream_t stream)
{
    const float* x    = (const float*)d_in[0];
    const float* w1o  = (const float*)d_in[1];
    const float* b1o  = (const float*)d_in[2];
    const float* w2o  = (const float*)d_in[3];
    const float* b2o  = (const float*)d_in[4];
    const float* w1g  = (const float*)d_in[5];
    const float* b1g  = (const float*)d_in[6];
    const float* w2g  = (const float*)d_in[7];
    const float* b2g  = (const float*)d_in[8];
    const float* beta = (const float*)d_in[9];
    float* out = (float*)d_out;
    float* wsf = (float*)d_ws;

    float* hid_o = wsf;
    float* hid_g = hid_o + (size_t)B_N * HIDC * NP;

    // output layout: y [4,21,324,324], v [4,8,81,81], g_up [4,1,324,324]
    float* y_out = out;
    float* v_out = out + (size_t)B_N * CIN * NPH;
    float* gup   = v_out + (size_t)B_N * 8 * NP;

    k1_conv1<<<dim3((NP + 255) / 256, 8, B_N), 256, 0, stream>>>(
        x, w1o, b1o, w1g, b1g, hid_o, hid_g);
    k2up<<<dim3((NP + 31) / 32, B_N), 256, 0, stream>>>(
        x, hid_o, hid_g, w2o, b2o, w2g, b2g, beta, v_out, y_out, gup);
}

// Round 5
// 143.804 us; speedup vs baseline: 1.3991x; 1.3991x over previous
//
#include <hip/hip_runtime.h>
#include <math.h>

// Problem constants
#define B_N   4
#define CIN   21
#define HIDC  48
#define H0    81
#define NP    6561      // 81*81
#define HH    324
#define NPH   104976    // 324*324

__device__ __forceinline__ float tanh_fast(float x) {
    float e = __expf(2.f * x);
    return 1.f - 2.f / (e + 1.f);
}

// ---------------------------------------------------------------------------
// K1 v6 (unchanged): conv1 both heads (21 -> 96 = 48 o + 48 g), relu.
// ---------------------------------------------------------------------------
__global__ __launch_bounds__(256) void k1_conv1(
    const float* __restrict__ x,
    const float* __restrict__ w1o, const float* __restrict__ b1o,
    const float* __restrict__ w1g, const float* __restrict__ b1g,
    float* __restrict__ hid_o, float* __restrict__ hid_g)
{
    __shared__ __align__(16) float wt[189 * 12];  // [ict*12 + oc]
    __shared__ float bs[12];
    const int tid = threadIdx.x;
    const int grp = blockIdx.y;          // 0..7 ; 0..3 -> head_o, 4..7 -> head_g
    const int b   = blockIdx.z;
    const bool head_o = (grp < 4);
    const int ocb = (grp & 3) * 12;      // oc base within the head
    const float* wsrc = head_o ? w1o : w1g;
    for (int i = tid; i < 189 * 12; i += 256) {
        const int ict = i / 12, oc = i - ict * 12;
        wt[i] = wsrc[(ocb + oc) * 189 + ict];
    }
    if (tid < 12) bs[tid] = (head_o ? b1o : b1g)[ocb + tid];
    __syncthreads();

    const int px = blockIdx.x * 256 + tid;
    const bool valid = (px < NP);
    const int oy = px / H0, ox = px - oy * H0;
    const float* xb = x + (size_t)b * CIN * NP;

    float acc[12];
    #pragma unroll
    for (int j = 0; j < 12; j++) acc[j] = bs[j];

    for (int ic = 0; ic < CIN; ic++) {
        const float* xc = xb + ic * NP;
        float xv[9];
        #pragma unroll
        for (int ky = 0; ky < 3; ky++) {
            const int iy = oy + ky - 1;
            const bool rok = valid && ((unsigned)iy < (unsigned)H0);
            #pragma unroll
            for (int kx = 0; kx < 3; kx++) {
                const int ix = ox + kx - 1;
                const bool ok = rok && ((unsigned)ix < (unsigned)H0);
                xv[ky * 3 + kx] = ok ? xc[iy * H0 + ix] : 0.f;
            }
        }
        #pragma unroll
        for (int tap = 0; tap < 9; tap++) {
            const float4 w0 = *(const float4*)&wt[(ic * 9 + tap) * 12];
            const float4 w1 = *(const float4*)&wt[(ic * 9 + tap) * 12 + 4];
            const float4 w2 = *(const float4*)&wt[(ic * 9 + tap) * 12 + 8];
            const float wj[12] = {w0.x, w0.y, w0.z, w0.w, w1.x, w1.y, w1.z, w1.w,
                                  w2.x, w2.y, w2.z, w2.w};
            const float xvt = xv[tap];
            #pragma unroll
            for (int j = 0; j < 12; j++) acc[j] = fmaf(xvt, wj[j], acc[j]);
        }
    }

    if (valid) {
        float* outp = (head_o ? hid_o : hid_g) + ((size_t)b * HIDC + ocb) * NP + px;
        #pragma unroll
        for (int j = 0; j < 12; j++) outp[j * NP] = fmaxf(acc[j], 0.f);
    }
}

// ---------------------------------------------------------------------------
// K2UP v3: conv2+masks+upsample. x staged in LDS (can't spill, unlike v2's
// register prefetch which the allocator spilled to scratch: FETCH/WRITE
// exploded 3-5x in round 4). Per block: 4 reflected rows x 21 ch x 81 cols
// = 27.2 KB, loaded fully coalesced at kernel start, drained by the first
// (weights) barrier. Emit phase is then pure LDS+VALU: no post-barrier
// global loads, no alp2/ahp2 round-trip, one fewer barrier than v1.
// LDS 52.6 KB -> 3 blocks/CU; VGPR stays ~108 (conv phase unchanged).
// ---------------------------------------------------------------------------
__global__ __launch_bounds__(256) void k2up(
    const float* __restrict__ x,
    const float* __restrict__ hid_o, const float* __restrict__ hid_g,
    const float* __restrict__ w2o, const float* __restrict__ b2o,
    const float* __restrict__ w2g, const float* __restrict__ b2g,
    const float* __restrict__ beta,
    float* __restrict__ v_out, float* __restrict__ y_out,
    float* __restrict__ gup_out)
{
    __shared__ __align__(16) float wo_s[HIDC * 9 * 8];  // 13824 B
    __shared__ float wg_s[HIDC * 9];                    // 1728 B
    __shared__ float red[4][32][12];                    // 6144 B
    __shared__ float res_s[32][29];                     // 3712 B, stride 29 coprime w/ 32
    __shared__ float xs[CIN][4][H0];                    // 27216 B: 4 reflected rows
    const int tid = threadIdx.x;
    const int b = blockIdx.y;

    const int pl  = tid & 31;
    const int s   = tid >> 5;                // 0..7
    const int w   = tid >> 6;                // wave
    const int px0 = blockIdx.x * 32;
    const int px  = px0 + pl;
    const bool valid = (px < NP);
    const int py  = px / H0, pxc = px - py * H0;
    const int pr0 = px0 / H0;                // first row touched by this block

    // ---- stage x rows: slot t = reflect(pr0-1+t), fully coalesced -------
    {
        const float* xb = x + (size_t)b * CIN * NP;
        for (int i = tid; i < CIN * 4 * H0; i += 256) {
            const int c = i / (4 * H0), rem = i - c * (4 * H0);
            const int t = rem / H0, col = rem - t * H0;
            int r = pr0 - 1 + t;
            r = (r < 0) ? -r : r;
            r = (r > H0 - 1) ? 2 * (H0 - 1) - r : r;
            (&xs[0][0][0])[i] = xb[c * NP + r * H0 + col];
        }
    }

    // ---- stage conv2 weights --------------------------------------------
    for (int i = tid; i < HIDC * 9 * 8; i += 256) {
        const int d = i / (HIDC * 9), r = i - d * (HIDC * 9);
        wo_s[r * 8 + d] = w2o[i];
    }
    for (int i = tid; i < HIDC * 9; i += 256) wg_s[i] = w2g[i];
    __syncthreads();

    // ---- conv2 partials (v1-proven structure, unchanged) ----------------
    const int ic0 = s * 6;
    const float* po = hid_o + ((size_t)b * HIDC + ic0) * NP;
    const float* pg = hid_g + ((size_t)b * HIDC + ic0) * NP;

    float a[8] = {0.f, 0.f, 0.f, 0.f, 0.f, 0.f, 0.f, 0.f};
    float ag = 0.f;

    #pragma unroll 1
    for (int ky = 0; ky < 3; ky++) {
        const int iy = py + ky - 1;
        const bool rok = valid && ((unsigned)iy < (unsigned)H0);
        #pragma unroll
        for (int kx = 0; kx < 3; kx++) {
            const int ix = pxc + kx - 1;
            const bool ok = rok && ((unsigned)ix < (unsigned)H0);
            const int off = iy * H0 + ix;
            const int tap = ky * 3 + kx;
            #pragma unroll
            for (int j = 0; j < 6; j++) {
                const float vo = ok ? po[j * NP + off] : 0.f;
                const float vg = ok ? pg[j * NP + off] : 0.f;
                const int wb = ((ic0 + j) * 9 + tap) * 8;
                const float4 wA = *(const float4*)&wo_s[wb];
                const float4 wB = *(const float4*)&wo_s[wb + 4];
                a[0] = fmaf(vo, wA.x, a[0]); a[1] = fmaf(vo, wA.y, a[1]);
                a[2] = fmaf(vo, wA.z, a[2]); a[3] = fmaf(vo, wA.w, a[3]);
                a[4] = fmaf(vo, wB.x, a[4]); a[5] = fmaf(vo, wB.y, a[5]);
                a[6] = fmaf(vo, wB.z, a[6]); a[7] = fmaf(vo, wB.w, a[7]);
                ag = fmaf(vg, wg_s[(ic0 + j) * 9 + tap], ag);
            }
        }
    }

    #pragma unroll
    for (int n = 0; n < 8; n++) a[n] += __shfl_xor(a[n], 32);
    ag += __shfl_xor(ag, 32);
    if ((tid & 32) == 0) {
        #pragma unroll
        for (int n = 0; n < 8; n++) red[w][pl][n] = a[n];
        red[w][pl][8] = ag;
    }
    __syncthreads();

    // ---- mask epilogue (32 threads) -------------------------------------
    if (tid < 32 && valid) {
        float v[8];
        #pragma unroll
        for (int n = 0; n < 8; n++)
            v[n] = tanh_fast(red[0][tid][n] + red[1][tid][n] + red[2][tid][n]
                             + red[3][tid][n] + b2o[n]);
        const float agf = red[0][tid][8] + red[1][tid][8] + red[2][tid][8]
                        + red[3][tid][8] + b2g[0];
        const float g = 1.f / (1.f + __expf(-agf));

        constexpr float DT[8][9] = {
            {-1, 0, 1, -1, 0, 1, -1, 0, 1},
            {-1,-1, 0, -1, 0, 1,  0, 1, 1},
            {-1,-1,-1,  0, 0, 0,  1, 1, 1},
            { 0,-1,-1,  1, 0,-1,  1, 1, 0},
            { 1, 0,-1,  1, 0,-1,  1, 0,-1},
            { 1, 1, 0,  1, 0,-1,  0,-1,-1},
            { 1, 1, 1,  0, 0, 0, -1,-1,-1},
            { 0, 1, 1, -1, 0, 1, -1,-1, 0}};
        float ker[9];
        #pragma unroll
        for (int n = 0; n < 9; n++) {
            float t = 0.f;
            #pragma unroll
            for (int d = 0; d < 8; d++) t += v[d] * DT[d][n];
            ker[n] = -0.125f * t;
        }
        ker[4] += 2.5f;
        float mx = ker[0];
        #pragma unroll
        for (int n = 1; n < 9; n++) mx = fmaxf(mx, ker[n]);
        float exn[9], sum = 0.f;
        #pragma unroll
        for (int n = 0; n < 9; n++) { exn[n] = __expf((ker[n] - mx) * 2.0f); sum += exn[n]; }
        const float rs = 1.f / sum;
        float mean = 0.f;
        #pragma unroll
        for (int n = 0; n < 9; n++) mean += ker[n];
        mean *= (1.f / 9.f);
        float den = 1e-8f;
        #pragma unroll
        for (int n = 0; n < 9; n++) den += fabsf(ker[n] - mean);
        const float rd = 1.f / den;

        #pragma unroll
        for (int n = 0; n < 8; n++) res_s[tid][n] = v[n];
        res_s[tid][8] = g;
        #pragma unroll
        for (int n = 0; n < 9; n++) {
            res_s[tid][9 + n]  = exn[n] * rs;
            res_s[tid][18 + n] = (ker[n] - mean) * rd;
        }
    }
    __syncthreads();

    // ---- v scatter (one iteration: 8 planes x 32 px) --------------------
    if (valid) v_out[((size_t)b * 8 + s) * NP + px] = res_s[pl][s];

    // ---- emit: 22 planes x 32 px items, all data from LDS ---------------
    const float tb = tanh_fast(beta[0]);
    for (int i = tid; i < 22 * 32; i += 256) {
        const int plane = i >> 5, pp = i & 31;
        const int p = px0 + pp;
        if (p >= NP) continue;
        const int ppy = p / H0, ppx = p - ppy * H0;
        const float gv = res_s[pp][8];

        if (plane == 21) {
            float* gdst = gup_out + (size_t)b * NPH;
            #pragma unroll
            for (int dh = 0; dh < 4; dh++)
                *reinterpret_cast<float4*>(gdst + (size_t)(ppy * 4 + dh) * HH + ppx * 4) =
                    make_float4(gv, gv, gv, gv);
            continue;
        }

        // 3x3 reflected window from LDS row cache
        const int d0 = ppy - pr0;        // 0 or 1
        const int xm = (ppx == 0) ? 1 : ppx - 1;
        const int xp = (ppx == H0 - 1) ? H0 - 2 : ppx + 1;
        float w9[9];
        #pragma unroll
        for (int t = 0; t < 3; t++) {
            w9[t * 3 + 0] = xs[plane][d0 + t][xm];
            w9[t * 3 + 1] = xs[plane][d0 + t][ppx];
            w9[t * 3 + 2] = xs[plane][d0 + t][xp];
        }

        float alp = 0.f, ahp = 0.f;
        #pragma unroll
        for (int t = 0; t < 9; t++) {
            alp = fmaf(w9[t], res_s[pp][9 + t],  alp);
            ahp = fmaf(w9[t], res_s[pp][18 + t], ahp);
        }

        const float lam = 0.15f * (1.f - gv);
        const float gh  = tb * gv;

        // per-pixel bilinear coefficients
        int sxv[4]; float wxv[4];
        #pragma unroll
        for (int k = 0; k < 4; k++) {
            const int W = ppx * 4 + k;
            const float xsf = (float)W * (80.f / 323.f);
            int x0 = (int)xsf;
            if (x0 > H0 - 2) x0 = H0 - 2;
            wxv[k] = xsf - (float)x0;
            sxv[k] = x0 - ppx + 1;       // 0 or 1
        }

        float* ydst = y_out + ((size_t)b * CIN + plane) * NPH;
        #pragma unroll
        for (int dh = 0; dh < 4; dh++) {
            const int H = ppy * 4 + dh;
            const float ysf = (float)H * (80.f / 323.f);
            int y0 = (int)ysf;
            if (y0 > H0 - 2) y0 = H0 - 2;
            const float wy = ysf - (float)y0;
            const int sy = y0 - ppy + 1;  // 0 or 1
            const float A0 = sy ? w9[3] : w9[0];
            const float A1 = sy ? w9[4] : w9[1];
            const float A2 = sy ? w9[5] : w9[2];
            const float B0 = sy ? w9[6] : w9[3];
            const float B1 = sy ? w9[7] : w9[4];
            const float B2 = sy ? w9[8] : w9[5];
            float rr[4];
            #pragma unroll
            for (int k = 0; k < 4; k++) {
                const float wx = wxv[k];
                const float top = sxv[k] ? fmaf(A2 - A1, wx, A1) : fmaf(A1 - A0, wx, A0);
                const float bot = sxv[k] ? fmaf(B2 - B1, wx, B1) : fmaf(B1 - B0, wx, B0);
                const float xup = fmaf(bot - top, wy, top);
                rr[k] = fmaf(lam, alp - xup, xup) + gh * ahp;
            }
            *reinterpret_cast<float4*>(ydst + (size_t)H * HH + ppx * 4) =
                make_float4(rr[0], rr[1], rr[2], rr[3]);
        }
    }
}

// ---------------------------------------------------------------------------
extern "C" void kernel_launch(void* const* d_in, const int* in_sizes, int n_in,
                              void* d_out, int out_size, void* d_ws, size_t ws_size,
                              hipStream_t stream)
{
    const float* x    = (const float*)d_in[0];
    const float* w1o  = (const float*)d_in[1];
    const float* b1o  = (const float*)d_in[2];
    const float* w2o  = (const float*)d_in[3];
    const float* b2o  = (const float*)d_in[4];
    const float* w1g  = (const float*)d_in[5];
    const float* b1g  = (const float*)d_in[6];
    const float* w2g  = (const float*)d_in[7];
    const float* b2g  = (const float*)d_in[8];
    const float* beta = (const float*)d_in[9];
    float* out = (float*)d_out;
    float* wsf = (float*)d_ws;

    float* hid_o = wsf;
    float* hid_g = hid_o + (size_t)B_N * HIDC * NP;

    // output layout: y [4,21,324,324], v [4,8,81,81], g_up [4,1,324,324]
    float* y_out = out;
    float* v_out = out + (size_t)B_N * CIN * NPH;
    float* gup   = v_out + (size_t)B_N * 8 * NP;

    k1_conv1<<<dim3((NP + 255) / 256, 8, B_N), 256, 0, stream>>>(
        x, w1o, b1o, w1g, b1g, hid_o, hid_g);
    k2up<<<dim3((NP + 31) / 32, B_N), 256, 0, stream>>>(
        x, hid_o, hid_g, w2o, b2o, w2g, b2g, beta, v_out, y_out, gup);
}